// Round 1
// baseline (165.615 us; speedup 1.0000x reference)
//
#include <hip/hip_runtime.h>
#include <hip/hip_bf16.h>
#include <math.h>

// Problem constants from the reference: B=4096, D=768, K=60.
// Output: scalar fp32 mean loss.
// loss_b = logsumexp(logits_b) - logits_b[0], where logits_b[0] = u_b . p_b,
// logits_b[1+k] = u_b . p_{neg_idx[b,k]}.

#define NB 4096
#define ND 768
#define NK 60
#define ND4 (ND / 4)          // 192 float4 per row
#define NLOGITS (NK + 1)      // 61

__global__ __launch_bounds__(256) void u2i_loss_kernel(
    const float* __restrict__ user,
    const float* __restrict__ items,
    const int* __restrict__ negidx,
    float* __restrict__ out)
{
    const int b    = blockIdx.x;
    const int tid  = threadIdx.x;
    const int wave = tid >> 6;
    const int lane = tid & 63;

    // Preload this row's user embedding: 192 float4, 64 lanes -> 3 float4/lane.
    const float4* u4 = (const float4*)user + (size_t)b * ND4;
    float4 u0 = u4[lane];
    float4 u1 = u4[64 + lane];
    float4 u2 = u4[128 + lane];

    __shared__ float logits[NLOGITS];

    const float4* it4 = (const float4*)items;
    const int* nrow = negidx + (size_t)b * NK;

    // 61 items distributed over 4 waves.
    for (int k = wave; k < NLOGITS; k += 4) {
        int row = (k == 0) ? b : nrow[k - 1];
        const float4* p4 = it4 + (size_t)row * ND4;
        float4 p0 = p4[lane];
        float4 p1 = p4[64 + lane];
        float4 p2 = p4[128 + lane];
        float acc = u0.x * p0.x + u0.y * p0.y + u0.z * p0.z + u0.w * p0.w;
        acc      += u1.x * p1.x + u1.y * p1.y + u1.z * p1.z + u1.w * p1.w;
        acc      += u2.x * p2.x + u2.y * p2.y + u2.z * p2.z + u2.w * p2.w;
        // 64-lane wave reduction.
        #pragma unroll
        for (int off = 32; off > 0; off >>= 1)
            acc += __shfl_down(acc, off, 64);
        if (lane == 0) logits[k] = acc;
    }
    __syncthreads();

    // First wave: logsumexp over 61 logits, then loss = lse - logits[0].
    if (tid < 64) {
        float v = (tid < NLOGITS) ? logits[tid] : -INFINITY;
        float m = v;
        #pragma unroll
        for (int off = 32; off > 0; off >>= 1)
            m = fmaxf(m, __shfl_down(m, off, 64));
        m = __shfl(m, 0, 64);
        float e = (tid < NLOGITS) ? __expf(v - m) : 0.0f;
        #pragma unroll
        for (int off = 32; off > 0; off >>= 1)
            e += __shfl_down(e, off, 64);
        if (tid == 0) {
            float loss = m + __logf(e) - logits[0];
            atomicAdd(out, loss * (1.0f / (float)NB));
        }
    }
}

extern "C" void kernel_launch(void* const* d_in, const int* in_sizes, int n_in,
                              void* d_out, int out_size, void* d_ws, size_t ws_size,
                              hipStream_t stream) {
    const float* user  = (const float*)d_in[0];   // (B, D) fp32
    const float* items = (const float*)d_in[1];   // (B, D) fp32
    const int*   negi  = (const int*)d_in[2];     // (B, K) int32
    float* out = (float*)d_out;                   // scalar fp32

    // d_out is poisoned with 0xAA before every timed call; zero it first.
    hipMemsetAsync(out, 0, sizeof(float), stream);

    u2i_loss_kernel<<<NB, 256, 0, stream>>>(user, items, negi, out);
}

// Round 2
// 152.244 us; speedup vs baseline: 1.0878x; 1.0878x over previous
//
#include <hip/hip_runtime.h>
#include <hip/hip_bf16.h>
#include <math.h>

// B=4096, D=768, K=60. Output: scalar fp32 mean CE loss, label 0.
// loss_b = logsumexp(logits_b) - logits_b[0].

#define NB 4096
#define ND 768
#define NK 60
#define ND4 (ND / 4)          // 192 float4 per row
#define NLOGITS (NK + 1)      // 61
#define NPAD 64               // padded logit count (3 dummies on row b)

__global__ __launch_bounds__(256) void u2i_loss_kernel(
    const float* __restrict__ user,
    const float* __restrict__ items,
    const int* __restrict__ negidx,
    float* __restrict__ out)
{
    const int b    = blockIdx.x;
    const int tid  = threadIdx.x;
    const int wave = tid >> 6;
    const int lane = tid & 63;

    __shared__ int   rows_s[NPAD];
    __shared__ float logits[NPAD];

    // Stage row indices: rows_s[0]=b (positive), rows_s[1..60]=neg, 61..63 dummy=b.
    if (tid < NPAD) {
        const int* nrow = negidx + (size_t)b * NK;
        rows_s[tid] = (tid == 0 || tid > NK) ? b : nrow[tid - 1];
    }

    // Preload user row: 192 float4 over 64 lanes -> 3 float4/lane.
    const float4* u4 = (const float4*)user + (size_t)b * ND4;
    float4 u0 = u4[lane];
    float4 u1 = u4[64 + lane];
    float4 u2 = u4[128 + lane];

    __syncthreads();

    const float4* it4 = (const float4*)items;

    // Each wave handles 16 of the 64 padded items (k = wave + 4*i),
    // in 4 chunks of 4 concurrent items for memory-level parallelism.
    #pragma unroll
    for (int j = 0; j < 4; ++j) {
        int ks[4];
        const float4* p[4];
        #pragma unroll
        for (int i = 0; i < 4; ++i) {
            ks[i] = wave + j * 16 + i * 4;
            p[i]  = it4 + (size_t)rows_s[ks[i]] * ND4;
        }
        // 12 float4 loads in flight.
        float4 v0[4], v1[4], v2[4];
        #pragma unroll
        for (int i = 0; i < 4; ++i) {
            v0[i] = p[i][lane];
            v1[i] = p[i][64 + lane];
            v2[i] = p[i][128 + lane];
        }
        float acc[4];
        #pragma unroll
        for (int i = 0; i < 4; ++i) {
            float a;
            a  = u0.x * v0[i].x + u0.y * v0[i].y + u0.z * v0[i].z + u0.w * v0[i].w;
            a += u1.x * v1[i].x + u1.y * v1[i].y + u1.z * v1[i].z + u1.w * v1[i].w;
            a += u2.x * v2[i].x + u2.y * v2[i].y + u2.z * v2[i].z + u2.w * v2[i].w;
            acc[i] = a;
        }
        // 4 independent 64-lane reductions, interleaved to hide shuffle latency.
        #pragma unroll
        for (int off = 32; off > 0; off >>= 1) {
            #pragma unroll
            for (int i = 0; i < 4; ++i)
                acc[i] += __shfl_down(acc[i], off, 64);
        }
        if (lane == 0) {
            #pragma unroll
            for (int i = 0; i < 4; ++i)
                logits[ks[i]] = acc[i];
        }
    }
    __syncthreads();

    // First wave: logsumexp over the 61 real logits; loss = lse - logits[0].
    if (tid < 64) {
        float v = (tid < NLOGITS) ? logits[tid] : -INFINITY;
        float m = v;
        #pragma unroll
        for (int off = 32; off > 0; off >>= 1)
            m = fmaxf(m, __shfl_down(m, off, 64));
        m = __shfl(m, 0, 64);
        float e = (tid < NLOGITS) ? __expf(v - m) : 0.0f;
        #pragma unroll
        for (int off = 32; off > 0; off >>= 1)
            e += __shfl_down(e, off, 64);
        if (tid == 0) {
            float loss = m + __logf(e) - logits[0];
            atomicAdd(out, loss * (1.0f / (float)NB));
        }
    }
}

extern "C" void kernel_launch(void* const* d_in, const int* in_sizes, int n_in,
                              void* d_out, int out_size, void* d_ws, size_t ws_size,
                              hipStream_t stream) {
    const float* user  = (const float*)d_in[0];   // (B, D) fp32
    const float* items = (const float*)d_in[1];   // (B, D) fp32
    const int*   negi  = (const int*)d_in[2];     // (B, K) int32
    float* out = (float*)d_out;                   // scalar fp32

    // d_out is re-poisoned before every timed call; zero it on-stream.
    hipMemsetAsync(out, 0, sizeof(float), stream);

    u2i_loss_kernel<<<NB, 256, 0, stream>>>(user, items, negi, out);
}

// Round 3
// 135.312 us; speedup vs baseline: 1.2239x; 1.1251x over previous
//
#include <hip/hip_runtime.h>
#include <hip/hip_bf16.h>
#include <hip/hip_fp16.h>
#include <math.h>

// B=4096, D=768, K=60. Output: scalar fp32 mean CE loss, label 0.
// loss_b = logsumexp(logits_b) - logits_b[0].
//
// Strategy: items table (12.6 MB fp32) is gathered randomly 61x per row ->
// 768 MB logical traffic, latency/L2-bound. Convert items to fp16 (6.3 MB)
// once per call into d_ws: halves gather bytes, near-fits per-XCD L2.

#define NB 4096
#define ND 768
#define NK 60
#define ND4 (ND / 4)          // 192 float4 per fp32 row
#define NDH2 (ND / 2)         // 384 half2 (uint) per fp16 row
#define NLOGITS (NK + 1)      // 61
#define NPAD 64

typedef _Float16 h2 __attribute__((ext_vector_type(2)));
typedef float    f2 __attribute__((ext_vector_type(2)));

// ---- pre-pass: fp32 items -> fp16 (packed as uint2 = 4 halves) ----
__global__ __launch_bounds__(256) void convert_items_f16(
    const float4* __restrict__ in, uint2* __restrict__ outh)
{
    int i = blockIdx.x * 256 + threadIdx.x;   // one float4 -> one uint2
    float4 v = in[i];
    h2 a = { (_Float16)v.x, (_Float16)v.y };
    h2 b = { (_Float16)v.z, (_Float16)v.w };
    uint2 r;
    r.x = __builtin_bit_cast(unsigned int, a);
    r.y = __builtin_bit_cast(unsigned int, b);
    outh[i] = r;
}

// ---- main gather-dot + logsumexp kernel (fp16 items) ----
__global__ __launch_bounds__(256) void u2i_loss_f16(
    const float* __restrict__ user,
    const uint2* __restrict__ itemsh,   // (B, ND/4) uint2 rows of packed fp16
    const int* __restrict__ negidx,
    float* __restrict__ out)
{
    const int b    = blockIdx.x;
    const int tid  = threadIdx.x;
    const int wave = tid >> 6;
    const int lane = tid & 63;

    __shared__ int   rows_s[NPAD];
    __shared__ float logits[NPAD];

    if (tid < NPAD) {
        const int* nrow = negidx + (size_t)b * NK;
        rows_s[tid] = (tid == 0 || tid > NK) ? b : nrow[tid - 1];
    }

    // user row fp32: 192 float4 over 64 lanes -> 3 float4/lane.
    // float4 index i covers elements 4i..4i+3; uint2 index i covers the same
    // 4 elements of the fp16 row -> layouts line up per lane.
    const float4* u4 = (const float4*)user + (size_t)b * ND4;
    float4 u0 = u4[lane];
    float4 u1 = u4[64 + lane];
    float4 u2 = u4[128 + lane];

    __syncthreads();

    // Each wave: 16 padded items (k = wave + 4*m), 2 chunks of 8 in flight.
    #pragma unroll
    for (int j = 0; j < 2; ++j) {
        int ks[8];
        const uint2* p[8];
        #pragma unroll
        for (int i = 0; i < 8; ++i) {
            ks[i] = wave + 4 * (j * 8 + i);
            p[i]  = itemsh + (size_t)rows_s[ks[i]] * (ND4);
        }
        uint2 v0[8], v1[8], v2[8];    // 24 dwordx2 loads in flight
        #pragma unroll
        for (int i = 0; i < 8; ++i) {
            v0[i] = p[i][lane];
            v1[i] = p[i][64 + lane];
            v2[i] = p[i][128 + lane];
        }
        float acc[8];
        #pragma unroll
        for (int i = 0; i < 8; ++i) {
            f2 a0 = __builtin_convertvector(__builtin_bit_cast(h2, v0[i].x), f2);
            f2 a1 = __builtin_convertvector(__builtin_bit_cast(h2, v0[i].y), f2);
            f2 b0 = __builtin_convertvector(__builtin_bit_cast(h2, v1[i].x), f2);
            f2 b1 = __builtin_convertvector(__builtin_bit_cast(h2, v1[i].y), f2);
            f2 c0 = __builtin_convertvector(__builtin_bit_cast(h2, v2[i].x), f2);
            f2 c1 = __builtin_convertvector(__builtin_bit_cast(h2, v2[i].y), f2);
            float a;
            a  = u0.x * a0.x + u0.y * a0.y + u0.z * a1.x + u0.w * a1.y;
            a += u1.x * b0.x + u1.y * b0.y + u1.z * b1.x + u1.w * b1.y;
            a += u2.x * c0.x + u2.y * c0.y + u2.z * c1.x + u2.w * c1.y;
            acc[i] = a;
        }
        #pragma unroll
        for (int off = 32; off > 0; off >>= 1) {
            #pragma unroll
            for (int i = 0; i < 8; ++i)
                acc[i] += __shfl_down(acc[i], off, 64);
        }
        if (lane == 0) {
            #pragma unroll
            for (int i = 0; i < 8; ++i)
                logits[ks[i]] = acc[i];
        }
    }
    __syncthreads();

    if (tid < 64) {
        float v = (tid < NLOGITS) ? logits[tid] : -INFINITY;
        float m = v;
        #pragma unroll
        for (int off = 32; off > 0; off >>= 1)
            m = fmaxf(m, __shfl_down(m, off, 64));
        m = __shfl(m, 0, 64);
        float e = (tid < NLOGITS) ? __expf(v - m) : 0.0f;
        #pragma unroll
        for (int off = 32; off > 0; off >>= 1)
            e += __shfl_down(e, off, 64);
        if (tid == 0) {
            float loss = m + __logf(e) - logits[0];
            atomicAdd(out, loss * (1.0f / (float)NB));
        }
    }
}

// ---- fallback (round-2 fp32 path) if ws is too small ----
__global__ __launch_bounds__(256) void u2i_loss_f32(
    const float* __restrict__ user,
    const float* __restrict__ items,
    const int* __restrict__ negidx,
    float* __restrict__ out)
{
    const int b    = blockIdx.x;
    const int tid  = threadIdx.x;
    const int wave = tid >> 6;
    const int lane = tid & 63;

    __shared__ int   rows_s[NPAD];
    __shared__ float logits[NPAD];

    if (tid < NPAD) {
        const int* nrow = negidx + (size_t)b * NK;
        rows_s[tid] = (tid == 0 || tid > NK) ? b : nrow[tid - 1];
    }
    const float4* u4 = (const float4*)user + (size_t)b * ND4;
    float4 u0 = u4[lane];
    float4 u1 = u4[64 + lane];
    float4 u2 = u4[128 + lane];
    __syncthreads();

    const float4* it4 = (const float4*)items;
    #pragma unroll
    for (int j = 0; j < 4; ++j) {
        int ks[4];
        const float4* p[4];
        #pragma unroll
        for (int i = 0; i < 4; ++i) {
            ks[i] = wave + j * 16 + i * 4;
            p[i]  = it4 + (size_t)rows_s[ks[i]] * ND4;
        }
        float4 v0[4], v1[4], v2[4];
        #pragma unroll
        for (int i = 0; i < 4; ++i) {
            v0[i] = p[i][lane];
            v1[i] = p[i][64 + lane];
            v2[i] = p[i][128 + lane];
        }
        float acc[4];
        #pragma unroll
        for (int i = 0; i < 4; ++i) {
            float a;
            a  = u0.x * v0[i].x + u0.y * v0[i].y + u0.z * v0[i].z + u0.w * v0[i].w;
            a += u1.x * v1[i].x + u1.y * v1[i].y + u1.z * v1[i].z + u1.w * v1[i].w;
            a += u2.x * v2[i].x + u2.y * v2[i].y + u2.z * v2[i].z + u2.w * v2[i].w;
            acc[i] = a;
        }
        #pragma unroll
        for (int off = 32; off > 0; off >>= 1) {
            #pragma unroll
            for (int i = 0; i < 4; ++i)
                acc[i] += __shfl_down(acc[i], off, 64);
        }
        if (lane == 0) {
            #pragma unroll
            for (int i = 0; i < 4; ++i)
                logits[ks[i]] = acc[i];
        }
    }
    __syncthreads();

    if (tid < 64) {
        float v = (tid < NLOGITS) ? logits[tid] : -INFINITY;
        float m = v;
        #pragma unroll
        for (int off = 32; off > 0; off >>= 1)
            m = fmaxf(m, __shfl_down(m, off, 64));
        m = __shfl(m, 0, 64);
        float e = (tid < NLOGITS) ? __expf(v - m) : 0.0f;
        #pragma unroll
        for (int off = 32; off > 0; off >>= 1)
            e += __shfl_down(e, off, 64);
        if (tid == 0) {
            float loss = m + __logf(e) - logits[0];
            atomicAdd(out, loss * (1.0f / (float)NB));
        }
    }
}

extern "C" void kernel_launch(void* const* d_in, const int* in_sizes, int n_in,
                              void* d_out, int out_size, void* d_ws, size_t ws_size,
                              hipStream_t stream) {
    const float* user  = (const float*)d_in[0];   // (B, D) fp32
    const float* items = (const float*)d_in[1];   // (B, D) fp32
    const int*   negi  = (const int*)d_in[2];     // (B, K) int32
    float* out = (float*)d_out;                   // scalar fp32

    hipMemsetAsync(out, 0, sizeof(float), stream);

    const size_t need = (size_t)NB * ND * sizeof(unsigned short);  // 6.3 MB
    if (ws_size >= need) {
        // (NB*ND/4) float4 elements = 786432 -> 3072 blocks of 256.
        convert_items_f16<<<(NB * ND / 4) / 256, 256, 0, stream>>>(
            (const float4*)items, (uint2*)d_ws);
        u2i_loss_f16<<<NB, 256, 0, stream>>>(user, (const uint2*)d_ws, negi, out);
    } else {
        u2i_loss_f32<<<NB, 256, 0, stream>>>(user, items, negi, out);
    }
}

// Round 4
// 108.589 us; speedup vs baseline: 1.5252x; 1.2461x over previous
//
#include <hip/hip_runtime.h>
#include <hip/hip_bf16.h>
#include <hip/hip_fp16.h>
#include <math.h>

// B=4096, D=768, K=60. Output: scalar fp32 mean CE loss, label 0.
// loss_b = logsumexp(logits_b) - logits_b[0].
//
// 4-phase structure, no same-address atomics, no intra-block barriers in the
// hot phase, one wave per 4 logits for maximal TLP (65536 waves).
// ws layout:
//   [0, 1MB)            logits, (4096 x 64) fp32 (61 real + 3 dummy)
//   [1MB, 1MB+6.29MB)   items as fp16 (4096 x 768)
//   [+, +16KB)          per-row loss (4096 fp32)

#define NB 4096
#define ND 768
#define NK 60
#define ND4 (ND / 4)           // 192: float4 per fp32 row == uint2 per fp16 row
#define NLOGITS (NK + 1)       // 61
#define NPAD 64

#define WS_LOGITS_OFF 0
#define WS_ITEMS_OFF  ((size_t)NB * NPAD * 4)                 // 1 MB
#define WS_LOSS_OFF   (WS_ITEMS_OFF + (size_t)NB * ND * 2)    // +6.29 MB
#define WS_NEED       (WS_LOSS_OFF + (size_t)NB * 4)

typedef _Float16 h2 __attribute__((ext_vector_type(2)));
typedef float    f2 __attribute__((ext_vector_type(2)));

// ---- phase 1: fp32 items -> fp16 (packed uint2 = 4 halves) ----
__global__ __launch_bounds__(256) void convert_items_f16(
    const float4* __restrict__ in, uint2* __restrict__ outh)
{
    int i = blockIdx.x * 256 + threadIdx.x;
    float4 v = in[i];
    h2 a = { (_Float16)v.x, (_Float16)v.y };
    h2 b = { (_Float16)v.z, (_Float16)v.w };
    uint2 r;
    r.x = __builtin_bit_cast(unsigned int, a);
    r.y = __builtin_bit_cast(unsigned int, b);
    outh[i] = r;
}

// ---- phase 2: one wave per 4 logits; 16 waves per row ----
__global__ __launch_bounds__(256) void gather_dots(
    const float* __restrict__ user,
    const uint2* __restrict__ itemsh,
    const int* __restrict__ negidx,
    float* __restrict__ logits)
{
    const int tid  = threadIdx.x;
    const int lane = tid & 63;
    const int w    = blockIdx.x * 4 + (tid >> 6);   // global wave id
    const int b    = w >> 4;                        // row
    const int slot = w & 15;                        // 4 logits per slot

    // user row fp32: 3 float4/lane (L2-resident, reused 16x per row)
    const float4* u4 = (const float4*)user + (size_t)b * ND4;
    float4 u0 = u4[lane];
    float4 u1 = u4[64 + lane];
    float4 u2 = u4[128 + lane];

    const int* nrow = negidx + (size_t)b * NK;
    const uint2* p[4];
    #pragma unroll
    for (int i = 0; i < 4; ++i) {
        int k = slot * 4 + i;
        int row = (k == 0 || k > NK) ? b : nrow[k - 1];
        p[i] = itemsh + (size_t)row * ND4;
    }

    // 12 gather loads in flight (8 B/lane each, contiguous within a row)
    uint2 v0[4], v1[4], v2[4];
    #pragma unroll
    for (int i = 0; i < 4; ++i) {
        v0[i] = p[i][lane];
        v1[i] = p[i][64 + lane];
        v2[i] = p[i][128 + lane];
    }

    float acc[4];
    #pragma unroll
    for (int i = 0; i < 4; ++i) {
        f2 a0 = __builtin_convertvector(__builtin_bit_cast(h2, v0[i].x), f2);
        f2 a1 = __builtin_convertvector(__builtin_bit_cast(h2, v0[i].y), f2);
        f2 b0 = __builtin_convertvector(__builtin_bit_cast(h2, v1[i].x), f2);
        f2 b1 = __builtin_convertvector(__builtin_bit_cast(h2, v1[i].y), f2);
        f2 c0 = __builtin_convertvector(__builtin_bit_cast(h2, v2[i].x), f2);
        f2 c1 = __builtin_convertvector(__builtin_bit_cast(h2, v2[i].y), f2);
        float a;
        a  = u0.x * a0.x + u0.y * a0.y + u0.z * a1.x + u0.w * a1.y;
        a += u1.x * b0.x + u1.y * b0.y + u1.z * b1.x + u1.w * b1.y;
        a += u2.x * c0.x + u2.y * c0.y + u2.z * c1.x + u2.w * c1.y;
        acc[i] = a;
    }

    // 4 interleaved 64-lane reductions
    #pragma unroll
    for (int off = 32; off > 0; off >>= 1) {
        #pragma unroll
        for (int i = 0; i < 4; ++i)
            acc[i] += __shfl_down(acc[i], off, 64);
    }

    if (lane == 0) {
        float4 st = { acc[0], acc[1], acc[2], acc[3] };
        ((float4*)logits)[(size_t)b * 16 + slot] = st;
    }
}

// ---- phase 3: one wave per row: logsumexp -> per-row loss ----
__global__ __launch_bounds__(256) void lse_loss(
    const float* __restrict__ logits, float* __restrict__ loss)
{
    const int tid  = threadIdx.x;
    const int lane = tid & 63;
    const int b    = blockIdx.x * 4 + (tid >> 6);

    float v  = (lane < NLOGITS) ? logits[(size_t)b * NPAD + lane] : -INFINITY;
    float p0 = __shfl(v, 0, 64);
    float m = v;
    #pragma unroll
    for (int off = 32; off > 0; off >>= 1)
        m = fmaxf(m, __shfl_down(m, off, 64));
    m = __shfl(m, 0, 64);
    float e = (lane < NLOGITS) ? __expf(v - m) : 0.0f;
    #pragma unroll
    for (int off = 32; off > 0; off >>= 1)
        e += __shfl_down(e, off, 64);
    if (lane == 0)
        loss[b] = m + __logf(e) - p0;
}

// ---- phase 4: single block reduces 4096 losses -> mean ----
__global__ __launch_bounds__(256) void final_reduce(
    const float* __restrict__ loss, float* __restrict__ out)
{
    const int tid = threadIdx.x;
    const float4* l4 = (const float4*)loss;   // 1024 float4
    float s = 0.0f;
    #pragma unroll
    for (int j = 0; j < 4; ++j) {
        float4 v = l4[tid + 256 * j];
        s += v.x + v.y + v.z + v.w;
    }
    #pragma unroll
    for (int off = 32; off > 0; off >>= 1)
        s += __shfl_down(s, off, 64);
    __shared__ float ps[4];
    if ((tid & 63) == 0) ps[tid >> 6] = s;
    __syncthreads();
    if (tid == 0)
        out[0] = (ps[0] + ps[1] + ps[2] + ps[3]) * (1.0f / (float)NB);
}

// ---- fallback (round-2 fp32 single-kernel path) if ws too small ----
__global__ __launch_bounds__(256) void u2i_loss_f32(
    const float* __restrict__ user,
    const float* __restrict__ items,
    const int* __restrict__ negidx,
    float* __restrict__ out)
{
    const int b    = blockIdx.x;
    const int tid  = threadIdx.x;
    const int wave = tid >> 6;
    const int lane = tid & 63;

    __shared__ int   rows_s[NPAD];
    __shared__ float logits[NPAD];

    if (tid < NPAD) {
        const int* nrow = negidx + (size_t)b * NK;
        rows_s[tid] = (tid == 0 || tid > NK) ? b : nrow[tid - 1];
    }
    const float4* u4 = (const float4*)user + (size_t)b * ND4;
    float4 u0 = u4[lane];
    float4 u1 = u4[64 + lane];
    float4 u2 = u4[128 + lane];
    __syncthreads();

    const float4* it4 = (const float4*)items;
    #pragma unroll
    for (int j = 0; j < 4; ++j) {
        int ks[4];
        const float4* p[4];
        #pragma unroll
        for (int i = 0; i < 4; ++i) {
            ks[i] = wave + j * 16 + i * 4;
            p[i]  = it4 + (size_t)rows_s[ks[i]] * ND4;
        }
        float4 v0[4], v1[4], v2[4];
        #pragma unroll
        for (int i = 0; i < 4; ++i) {
            v0[i] = p[i][lane];
            v1[i] = p[i][64 + lane];
            v2[i] = p[i][128 + lane];
        }
        float acc[4];
        #pragma unroll
        for (int i = 0; i < 4; ++i) {
            float a;
            a  = u0.x * v0[i].x + u0.y * v0[i].y + u0.z * v0[i].z + u0.w * v0[i].w;
            a += u1.x * v1[i].x + u1.y * v1[i].y + u1.z * v1[i].z + u1.w * v1[i].w;
            a += u2.x * v2[i].x + u2.y * v2[i].y + u2.z * v2[i].z + u2.w * v2[i].w;
            acc[i] = a;
        }
        #pragma unroll
        for (int off = 32; off > 0; off >>= 1) {
            #pragma unroll
            for (int i = 0; i < 4; ++i)
                acc[i] += __shfl_down(acc[i], off, 64);
        }
        if (lane == 0) {
            #pragma unroll
            for (int i = 0; i < 4; ++i)
                logits[ks[i]] = acc[i];
        }
    }
    __syncthreads();

    if (tid < 64) {
        float v = (tid < NLOGITS) ? logits[tid] : -INFINITY;
        float m = v;
        #pragma unroll
        for (int off = 32; off > 0; off >>= 1)
            m = fmaxf(m, __shfl_down(m, off, 64));
        m = __shfl(m, 0, 64);
        float e = (tid < NLOGITS) ? __expf(v - m) : 0.0f;
        #pragma unroll
        for (int off = 32; off > 0; off >>= 1)
            e += __shfl_down(e, off, 64);
        if (tid == 0) {
            float loss = m + __logf(e) - logits[0];
            atomicAdd(out, loss * (1.0f / (float)NB));
        }
    }
}

extern "C" void kernel_launch(void* const* d_in, const int* in_sizes, int n_in,
                              void* d_out, int out_size, void* d_ws, size_t ws_size,
                              hipStream_t stream) {
    const float* user  = (const float*)d_in[0];   // (B, D) fp32
    const float* items = (const float*)d_in[1];   // (B, D) fp32
    const int*   negi  = (const int*)d_in[2];     // (B, K) int32
    float* out = (float*)d_out;                   // scalar fp32

    if (ws_size >= WS_NEED) {
        char* ws = (char*)d_ws;
        float* logits = (float*)(ws + WS_LOGITS_OFF);
        uint2* itemsh = (uint2*)(ws + WS_ITEMS_OFF);
        float* loss   = (float*)(ws + WS_LOSS_OFF);

        convert_items_f16<<<(NB * ND / 4) / 256, 256, 0, stream>>>(
            (const float4*)items, itemsh);
        // 4096 rows x 16 waves = 65536 waves = 16384 blocks of 4 waves
        gather_dots<<<NB * 16 / 4, 256, 0, stream>>>(user, itemsh, negi, logits);
        lse_loss<<<NB / 4, 256, 0, stream>>>(logits, loss);
        final_reduce<<<1, 256, 0, stream>>>(loss, out);
    } else {
        hipMemsetAsync(out, 0, sizeof(float), stream);
        u2i_loss_f32<<<NB, 256, 0, stream>>>(user, items, negi, out);
    }
}

// Round 5
// 103.339 us; speedup vs baseline: 1.6026x; 1.0508x over previous
//
#include <hip/hip_runtime.h>
#include <hip/hip_bf16.h>
#include <hip/hip_fp16.h>
#include <math.h>

// B=4096, D=768, K=60. Output: scalar fp32 mean CE loss, label 0.
// loss_b = logsumexp(logits_b) - logits_b[0].
//
// Phases (no same-address atomics, no barriers in the hot phase):
//   1. convert user+items fp32 -> fp16 (packed) into ws
//   2. gather_dots: one wave per 8 logits (8 waves/row, 32768 waves),
//      v_dot2_f32_f16 inner product, 16 gather loads in flight/wave
//   3. lse_loss: one wave per row -> per-row loss
//   4. final_reduce: one block -> mean into d_out
//
// ws layout:
//   [0, 1MB)        logits (4096 x 64 fp32; 61 real + 3 dummy)
//   [+1MB, +6.29MB) items fp16 (4096 x 768)
//   [+,    +6.29MB) user  fp16 (4096 x 768)
//   [+, +16KB)      per-row loss (4096 fp32)

#define NB 4096
#define ND 768
#define NK 60
#define ND4  (ND / 4)          // 192 float4 per fp32 row
#define NDU  (ND / 2)          // 384 uints per fp16 row
#define NLOGITS (NK + 1)       // 61
#define NPAD 64

#define WS_LOGITS_OFF 0
#define WS_ITEMS_OFF  ((size_t)NB * NPAD * 4)                   // 1 MB
#define WS_USER_OFF   (WS_ITEMS_OFF + (size_t)NB * ND * 2)      // +6.29 MB
#define WS_LOSS_OFF   (WS_USER_OFF + (size_t)NB * ND * 2)       // +6.29 MB
#define WS_NEED       (WS_LOSS_OFF + (size_t)NB * 4)

typedef _Float16 h2 __attribute__((ext_vector_type(2)));
typedef float    f2 __attribute__((ext_vector_type(2)));

__device__ __forceinline__ float dot2_acc(unsigned int u, unsigned int v, float c) {
#if __has_builtin(__builtin_amdgcn_fdot2)
    return __builtin_amdgcn_fdot2(__builtin_bit_cast(h2, u),
                                  __builtin_bit_cast(h2, v), c, false);
#else
    f2 a = __builtin_convertvector(__builtin_bit_cast(h2, u), f2);
    f2 b = __builtin_convertvector(__builtin_bit_cast(h2, v), f2);
    return c + a.x * b.x + a.y * b.y;
#endif
}

// ---- phase 1: both tables fp32 -> fp16 (packed uint2 = 4 halves) ----
__global__ __launch_bounds__(256) void convert_f16(
    const float4* __restrict__ user, const float4* __restrict__ items,
    uint2* __restrict__ userh, uint2* __restrict__ itemsh)
{
    int i = blockIdx.x * 256 + threadIdx.x;
    float4 u = user[i];
    float4 v = items[i];
    h2 ua = { (_Float16)u.x, (_Float16)u.y };
    h2 ub = { (_Float16)u.z, (_Float16)u.w };
    h2 va = { (_Float16)v.x, (_Float16)v.y };
    h2 vb = { (_Float16)v.z, (_Float16)v.w };
    uint2 ru, rv;
    ru.x = __builtin_bit_cast(unsigned int, ua);
    ru.y = __builtin_bit_cast(unsigned int, ub);
    rv.x = __builtin_bit_cast(unsigned int, va);
    rv.y = __builtin_bit_cast(unsigned int, vb);
    userh[i]  = ru;
    itemsh[i] = rv;
}

// ---- phase 2: one wave per 8 logits; 8 waves per row ----
__global__ __launch_bounds__(256) void gather_dots(
    const unsigned int* __restrict__ userh,
    const unsigned int* __restrict__ itemsh,
    const int* __restrict__ negidx,
    float* __restrict__ logits)
{
    const int tid  = threadIdx.x;
    const int lane = tid & 63;
    const int w    = blockIdx.x * 4 + (tid >> 6);   // global wave id
    const int b    = w >> 3;                        // row
    const int slot = w & 7;                         // 8 logits per slot

    // 8 row indices (wave-uniform -> scalar loads)
    const int* nrow = negidx + (size_t)b * NK;
    int rows[8];
    #pragma unroll
    for (int i = 0; i < 8; ++i) {
        int k = slot * 8 + i;
        rows[i] = (k == 0 || k > NK) ? b : nrow[k - 1];
    }

    // user row fp16: uint4 (halves 8l..8l+7) + uint2 (halves 512+4l..512+4l+3)
    const unsigned int* ur = userh + (size_t)b * NDU;
    uint4 ua = ((const uint4*)ur)[lane];
    uint2 ub = ((const uint2*)(ur + 256))[lane];

    // 16 gather loads in flight
    uint4 va[8];
    uint2 vb[8];
    #pragma unroll
    for (int i = 0; i < 8; ++i) {
        const unsigned int* ir = itemsh + (size_t)rows[i] * NDU;
        va[i] = ((const uint4*)ir)[lane];
        vb[i] = ((const uint2*)(ir + 256))[lane];
    }

    float acc[8];
    #pragma unroll
    for (int i = 0; i < 8; ++i) {
        float a = 0.0f;
        a = dot2_acc(ua.x, va[i].x, a);
        a = dot2_acc(ua.y, va[i].y, a);
        a = dot2_acc(ua.z, va[i].z, a);
        a = dot2_acc(ua.w, va[i].w, a);
        a = dot2_acc(ub.x, vb[i].x, a);
        a = dot2_acc(ub.y, vb[i].y, a);
        acc[i] = a;
    }

    // 8 interleaved 64-lane reductions
    #pragma unroll
    for (int off = 32; off > 0; off >>= 1) {
        #pragma unroll
        for (int i = 0; i < 8; ++i)
            acc[i] += __shfl_down(acc[i], off, 64);
    }

    if (lane == 0) {
        float4* dst = (float4*)(logits + (size_t)b * NPAD + slot * 8);
        float4 s0 = { acc[0], acc[1], acc[2], acc[3] };
        float4 s1 = { acc[4], acc[5], acc[6], acc[7] };
        dst[0] = s0;
        dst[1] = s1;
    }
}

// ---- phase 3: one wave per row: logsumexp -> per-row loss ----
__global__ __launch_bounds__(256) void lse_loss(
    const float* __restrict__ logits, float* __restrict__ loss)
{
    const int tid  = threadIdx.x;
    const int lane = tid & 63;
    const int b    = blockIdx.x * 4 + (tid >> 6);

    float v  = (lane < NLOGITS) ? logits[(size_t)b * NPAD + lane] : -INFINITY;
    float p0 = __shfl(v, 0, 64);
    float m = v;
    #pragma unroll
    for (int off = 32; off > 0; off >>= 1)
        m = fmaxf(m, __shfl_down(m, off, 64));
    m = __shfl(m, 0, 64);
    float e = (lane < NLOGITS) ? __expf(v - m) : 0.0f;
    #pragma unroll
    for (int off = 32; off > 0; off >>= 1)
        e += __shfl_down(e, off, 64);
    if (lane == 0)
        loss[b] = m + __logf(e) - p0;
}

// ---- phase 4: single block reduces 4096 losses -> mean ----
__global__ __launch_bounds__(256) void final_reduce(
    const float* __restrict__ loss, float* __restrict__ out)
{
    const int tid = threadIdx.x;
    const float4* l4 = (const float4*)loss;   // 1024 float4
    float s = 0.0f;
    #pragma unroll
    for (int j = 0; j < 4; ++j) {
        float4 v = l4[tid + 256 * j];
        s += v.x + v.y + v.z + v.w;
    }
    #pragma unroll
    for (int off = 32; off > 0; off >>= 1)
        s += __shfl_down(s, off, 64);
    __shared__ float ps[4];
    if ((tid & 63) == 0) ps[tid >> 6] = s;
    __syncthreads();
    if (tid == 0)
        out[0] = (ps[0] + ps[1] + ps[2] + ps[3]) * (1.0f / (float)NB);
}

// ---- fallback (fp32 single-kernel path) if ws too small ----
__global__ __launch_bounds__(256) void u2i_loss_f32(
    const float* __restrict__ user,
    const float* __restrict__ items,
    const int* __restrict__ negidx,
    float* __restrict__ out)
{
    const int b    = blockIdx.x;
    const int tid  = threadIdx.x;
    const int wave = tid >> 6;
    const int lane = tid & 63;

    __shared__ int   rows_s[NPAD];
    __shared__ float logits[NPAD];

    if (tid < NPAD) {
        const int* nrow = negidx + (size_t)b * NK;
        rows_s[tid] = (tid == 0 || tid > NK) ? b : nrow[tid - 1];
    }
    const float4* u4 = (const float4*)user + (size_t)b * ND4;
    float4 u0 = u4[lane];
    float4 u1 = u4[64 + lane];
    float4 u2 = u4[128 + lane];
    __syncthreads();

    const float4* it4 = (const float4*)items;
    #pragma unroll
    for (int j = 0; j < 4; ++j) {
        int ks[4];
        const float4* p[4];
        #pragma unroll
        for (int i = 0; i < 4; ++i) {
            ks[i] = wave + j * 16 + i * 4;
            p[i]  = it4 + (size_t)rows_s[ks[i]] * ND4;
        }
        float4 v0[4], v1[4], v2[4];
        #pragma unroll
        for (int i = 0; i < 4; ++i) {
            v0[i] = p[i][lane];
            v1[i] = p[i][64 + lane];
            v2[i] = p[i][128 + lane];
        }
        float acc[4];
        #pragma unroll
        for (int i = 0; i < 4; ++i) {
            float a;
            a  = u0.x * v0[i].x + u0.y * v0[i].y + u0.z * v0[i].z + u0.w * v0[i].w;
            a += u1.x * v1[i].x + u1.y * v1[i].y + u1.z * v1[i].z + u1.w * v1[i].w;
            a += u2.x * v2[i].x + u2.y * v2[i].y + u2.z * v2[i].z + u2.w * v2[i].w;
            acc[i] = a;
        }
        #pragma unroll
        for (int off = 32; off > 0; off >>= 1) {
            #pragma unroll
            for (int i = 0; i < 4; ++i)
                acc[i] += __shfl_down(acc[i], off, 64);
        }
        if (lane == 0) {
            #pragma unroll
            for (int i = 0; i < 4; ++i)
                logits[ks[i]] = acc[i];
        }
    }
    __syncthreads();

    if (tid < 64) {
        float v = (tid < NLOGITS) ? logits[tid] : -INFINITY;
        float m = v;
        #pragma unroll
        for (int off = 32; off > 0; off >>= 1)
            m = fmaxf(m, __shfl_down(m, off, 64));
        m = __shfl(m, 0, 64);
        float e = (tid < NLOGITS) ? __expf(v - m) : 0.0f;
        #pragma unroll
        for (int off = 32; off > 0; off >>= 1)
            e += __shfl_down(e, off, 64);
        if (tid == 0) {
            float loss = m + __logf(e) - logits[0];
            atomicAdd(out, loss * (1.0f / (float)NB));
        }
    }
}

extern "C" void kernel_launch(void* const* d_in, const int* in_sizes, int n_in,
                              void* d_out, int out_size, void* d_ws, size_t ws_size,
                              hipStream_t stream) {
    const float* user  = (const float*)d_in[0];   // (B, D) fp32
    const float* items = (const float*)d_in[1];   // (B, D) fp32
    const int*   negi  = (const int*)d_in[2];     // (B, K) int32
    float* out = (float*)d_out;                   // scalar fp32

    if (ws_size >= WS_NEED) {
        char* ws = (char*)d_ws;
        float*        logits = (float*)(ws + WS_LOGITS_OFF);
        uint2*        itemsh = (uint2*)(ws + WS_ITEMS_OFF);
        uint2*        userh  = (uint2*)(ws + WS_USER_OFF);
        float*        loss   = (float*)(ws + WS_LOSS_OFF);

        // (NB*ND/4) float4 per table = 786432 -> 3072 blocks of 256
        convert_f16<<<(NB * ND / 4) / 256, 256, 0, stream>>>(
            (const float4*)user, (const float4*)items, userh, itemsh);
        // 4096 rows x 8 waves = 32768 waves = 8192 blocks of 4 waves
        gather_dots<<<NB * 8 / 4, 256, 0, stream>>>(
            (const unsigned int*)userh, (const unsigned int*)itemsh, negi, logits);
        lse_loss<<<NB / 4, 256, 0, stream>>>(logits, loss);
        final_reduce<<<1, 256, 0, stream>>>(loss, out);
    } else {
        hipMemsetAsync(out, 0, sizeof(float), stream);
        u2i_loss_f32<<<NB, 256, 0, stream>>>(user, items, negi, out);
    }
}